// Round 3
// baseline (464.289 us; speedup 1.0000x reference)
//
#include <hip/hip_runtime.h>
#include <math.h>

#define BB 16
#define NN 4096
#define M_TOT (BB*NN)   // 65536 points

typedef __attribute__((ext_vector_type(8))) short s8v;   // 8 bf16 = 4 VGPRs
typedef __attribute__((ext_vector_type(4))) float f4v;

// exact tanh-GELU via sigmoid identity: 0.5x(1+tanh(z)) = x * sigmoid(2z)
__device__ __forceinline__ float gelu_t(float x){
    float u = 1.5957691216057308f * x * (1.0f + 0.044715f*x*x);
    return x / (1.0f + __expf(-u));
}

__device__ __forceinline__ unsigned short f2bf(float f){
    unsigned int u = __float_as_uint(f);
    u += 0x7fffu + ((u >> 16) & 1u);
    return (unsigned short)(u >> 16);
}

// ---------------- chunked-staging conv device fn: CHUNK channels per barrier ----------------
template<int CIN, int COUT, int STRIDE, int CHUNK>
__device__ __forceinline__ void conv_dev2(
    const float* __restrict__ in, const float* __restrict__ w,
    const float* __restrict__ bias, float* __restrict__ out,
    int Hin, int Win, int Hout, int Wout, int bx, int by, int b, float* tile)
{
    constexpr int IW = 15*STRIDE + 3;
    constexpr int IH = IW;
    constexpr int PITCH = IW + 1;
    int tid = threadIdx.x;
    int tx = tid & 15, ty = tid >> 4;
    int wo = bx*16 + tx;
    int ho = by*16 + ty;
    int win0 = bx*16*STRIDE - 1;
    int hin0 = by*16*STRIDE - 1;
    bool valid = (wo < Wout) && (ho < Hout);

    float acc[COUT];
    #pragma unroll
    for (int co = 0; co < COUT; ++co) acc[co] = bias[co];

    const float* ib = in + (size_t)(b*CIN)*Hin*Win;
    for (int ci0 = 0; ci0 < CIN; ci0 += CHUNK) {
        __syncthreads();
        for (int idx = tid; idx < CHUNK*IH*IW; idx += 256) {
            int c = idx / (IH*IW), rem = idx - c*(IH*IW);
            int r = rem / IW, cc = rem - r*IW;
            int hi = hin0 + r, wi = win0 + cc;
            float v = 0.f;
            if ((unsigned)hi < (unsigned)Hin && (unsigned)wi < (unsigned)Win)
                v = ib[(size_t)(ci0 + c)*Hin*Win + hi*Win + wi];
            tile[c*IH*PITCH + r*PITCH + cc] = v;
        }
        __syncthreads();
        for (int ci = 0; ci < CHUNK; ++ci) {
            float vv[9];
            const float* tb = tile + ci*IH*PITCH;
            #pragma unroll
            for (int kh = 0; kh < 3; ++kh)
                #pragma unroll
                for (int kw = 0; kw < 3; ++kw)
                    vv[kh*3+kw] = tb[(ty*STRIDE + kh)*PITCH + tx*STRIDE + kw];
            const float* wc = w + (ci0 + ci)*9;
            #pragma unroll
            for (int co = 0; co < COUT; ++co) {
                const float* wp = wc + co*CIN*9;
                #pragma unroll
                for (int k = 0; k < 9; ++k)
                    acc[co] = fmaf(vv[k], wp[k], acc[co]);
            }
        }
    }
    if (valid) {
        size_t obase = ((size_t)b*COUT)*Hout*Wout + (size_t)ho*Wout + wo;
        #pragma unroll
        for (int co = 0; co < COUT; ++co)
            out[obase + (size_t)co*Hout*Wout] = gelu_t(acc[co]);
    }
}

// ---------------- dual conv1: plane (16ch) + global (4ch), all 3 ci staged once ----------------
__global__ __launch_bounds__(256) void conv_dual_k(
    const float* __restrict__ in,
    const float* __restrict__ wA, const float* __restrict__ bA,
    const float* __restrict__ wB, const float* __restrict__ bB,
    float* __restrict__ outA, float* __restrict__ outB)
{
    __shared__ float tile[3*33*34];   // 13.5 KB
    const int Hin = 224, Win = 224, Hout = 112, Wout = 112;
    int tid = threadIdx.x;
    int tx = tid & 15, ty = tid >> 4;
    int b = blockIdx.z;
    int wo = blockIdx.x*16 + tx;
    int ho = blockIdx.y*16 + ty;
    int win0 = blockIdx.x*32 - 1;
    int hin0 = blockIdx.y*32 - 1;

    const float* ib = in + (size_t)(b*3)*Hin*Win;
    for (int idx = tid; idx < 3*1089; idx += 256) {
        int c = idx / 1089, rem = idx - c*1089;
        int r = rem / 33, cc = rem - r*33;
        int hi = hin0 + r, wi = win0 + cc;
        float v = 0.f;
        if ((unsigned)hi < (unsigned)Hin && (unsigned)wi < (unsigned)Win)
            v = ib[(size_t)c*Hin*Win + hi*Win + wi];
        tile[c*33*34 + r*34 + cc] = v;
    }
    __syncthreads();

    float accA[16], accB[4];
    #pragma unroll
    for (int co = 0; co < 16; ++co) accA[co] = bA[co];
    #pragma unroll
    for (int co = 0; co < 4; ++co) accB[co] = bB[co];

    #pragma unroll
    for (int ci = 0; ci < 3; ++ci) {
        float vv[9];
        const float* tb = tile + ci*33*34;
        #pragma unroll
        for (int kh = 0; kh < 3; ++kh)
            #pragma unroll
            for (int kw = 0; kw < 3; ++kw)
                vv[kh*3+kw] = tb[(ty*2 + kh)*34 + tx*2 + kw];
        #pragma unroll
        for (int co = 0; co < 16; ++co) {
            const float* wp = wA + co*27 + ci*9;
            #pragma unroll
            for (int k = 0; k < 9; ++k) accA[co] = fmaf(vv[k], wp[k], accA[co]);
        }
        #pragma unroll
        for (int co = 0; co < 4; ++co) {
            const float* wp = wB + co*27 + ci*9;
            #pragma unroll
            for (int k = 0; k < 9; ++k) accB[co] = fmaf(vv[k], wp[k], accB[co]);
        }
    }
    size_t px = (size_t)ho*Wout + wo;
    #pragma unroll
    for (int co = 0; co < 16; ++co)
        outA[((size_t)(b*16 + co))*Hout*Wout + px] = gelu_t(accA[co]);
    #pragma unroll
    for (int co = 0; co < 4; ++co)
        outB[((size_t)(b*4 + co))*Hout*Wout + px] = gelu_t(accB[co]);
}

// ---------------- layer-2 convs: plane p2 (16->32, split co 2x16) + global g2 (4->8) ----------------
__global__ __launch_bounds__(256) void conv_pg2_k(
    const float* __restrict__ f1, const float* __restrict__ pw2, const float* __restrict__ pb2, float* __restrict__ f2,
    const float* __restrict__ g1, const float* __restrict__ gw2, const float* __restrict__ gb2, float* __restrict__ g2)
{
    __shared__ float tile[8*33*34];   // 35.9 KB
    int z = blockIdx.z;
    if (z < 32) {
        int b = z >> 1, half = z & 1;
        conv_dev2<16,16,2,8>(f1 + (size_t)b*16*12544, pw2 + half*2304, pb2 + half*16,
                             f2 + ((size_t)(b*32 + half*16))*3136,
                             112,112, 56,56, blockIdx.x, blockIdx.y, 0, tile);
    } else {
        conv_dev2<4,8,2,4>(g1, gw2, gb2, g2, 112,112, 56,56, blockIdx.x, blockIdx.y, z-32, tile);
    }
}

// ---------------- layer-3: plane p3 DIRECT (32->4, NHWC out) + global g3 (8->16, LDS) ----------------
__global__ __launch_bounds__(256) void conv_pg3_k(
    const float* __restrict__ f2, const float* __restrict__ pw3, const float* __restrict__ pb3, float4* __restrict__ fmap4,
    const float* __restrict__ g2, const float* __restrict__ gw3, const float* __restrict__ gb3, float* __restrict__ g3)
{
    __shared__ float tile[8*33*34];
    int z = blockIdx.z;
    if (z < 16) {
        int b = z;
        int idx = blockIdx.x*256 + threadIdx.x;
        if (idx >= 3136) return;
        int ho = idx / 56, wo = idx - ho*56;
        const float* ib = f2 + (size_t)b*32*3136;
        float acc[4];
        #pragma unroll
        for (int co = 0; co < 4; ++co) acc[co] = pb3[co];
        for (int ci = 0; ci < 32; ++ci) {
            const float* ic = ib + (size_t)ci*3136;
            #pragma unroll
            for (int kh = 0; kh < 3; ++kh) {
                int hi = ho - 1 + kh;
                if ((unsigned)hi >= 56u) continue;
                #pragma unroll
                for (int kw = 0; kw < 3; ++kw) {
                    int wi = wo - 1 + kw;
                    if ((unsigned)wi >= 56u) continue;
                    float v = ic[hi*56 + wi];
                    int wofs = ci*9 + kh*3 + kw;
                    #pragma unroll
                    for (int co = 0; co < 4; ++co)
                        acc[co] = fmaf(v, pw3[co*288 + wofs], acc[co]);
                }
            }
        }
        float4 o;
        o.x = gelu_t(acc[0]); o.y = gelu_t(acc[1]);
        o.z = gelu_t(acc[2]); o.w = gelu_t(acc[3]);
        fmap4[(size_t)b*3136 + idx] = o;
    } else {
        if (blockIdx.x >= 4) return;
        int bx = blockIdx.x & 1, by = blockIdx.x >> 1;
        conv_dev2<8,16,2,8>(g2, gw3, gb3, g3, 56,56, 28,28, bx, by, z-16, tile);
    }
}

// ================= K4: g4 (392 blocks) + patch fill (16384 blocks) =================
// Patch fill: tap spacing is exactly 1.0 pixel -> all 64 taps of a point share
// one fractional weight pair and lie on an integer 9x9 window. Per wave:
// cooperatively load the 9x9 float4 window into LDS (zero-fill OOB == validity
// masking), then each lane blends its 4 corners with shared wx/wy weights.
__global__ __launch_bounds__(256) void k4_k(
    const float* __restrict__ g3, const float* __restrict__ w4,
    const float* __restrict__ b4, float* __restrict__ g4o,
    const float4* __restrict__ fmap4, const float* __restrict__ points,
    unsigned short* __restrict__ C)
{
    __shared__ float4 pt[4*81];   // 5.2 KB: 4 waves x 9x9 window
    int bid = blockIdx.x;
    int tid = threadIdx.x;
    if (bid < 392) {
        int idx = bid*256 + tid;
        int co = idx & 31;
        int t = idx >> 5;
        int b = t / 196, px = t - b*196;
        int ho = px / 14, wo = px - ho*14;
        const float* src = g3 + (size_t)b*16*784;
        const float* wp = w4 + co*144;
        float acc = b4[co];
        for (int ci = 0; ci < 16; ++ci) {
            #pragma unroll
            for (int kh = 0; kh < 3; ++kh) {
                int hi = ho*2 - 1 + kh;
                if ((unsigned)hi >= 28u) continue;
                #pragma unroll
                for (int kw = 0; kw < 3; ++kw) {
                    int wi = wo*2 - 1 + kw;
                    if ((unsigned)wi >= 28u) continue;
                    acc = fmaf(src[ci*784 + hi*28 + wi], wp[ci*9 + kh*3 + kw], acc);
                }
            }
        }
        g4o[(size_t)b*6272 + px*32 + co] = gelu_t(acc);
    } else {
        int task = (bid - 392)*256 + tid;     // M*64 tasks, exact
        int wv = tid >> 6, lane = tid & 63;
        size_t m = (size_t)(task >> 6);       // wave-uniform point index
        int ij = task & 63;
        int i = ij >> 3, j = ij & 7;          // i: x tap index, j: y tap index
        int b = (int)(m >> 12);
        float px = points[m*2], py = points[m*2+1];
        // ix = 55*px + (i-3.5): integer tap spacing -> shared fractional weights
        float X = fmaf(px, 55.f, -3.5f);      // = ix at i=0
        float Y = fmaf(py, 55.f, -3.5f);
        float xbf = floorf(X), ybf = floorf(Y);
        int xbase = (int)xbf, ybase = (int)ybf;
        float wx1 = X - xbf, wx0 = 1.f - wx1;
        float wy1 = Y - ybf, wy0 = 1.f - wy1;
        const float4* fb = fmap4 + (size_t)b*3136;
        float4* tp = pt + wv*81;

        // cooperative load: 81 float4 (rows = y, cols = x), zero-fill OOB
        {
            int r = lane / 9, c = lane - r*9;
            int y = ybase + r, x = xbase + c;
            float4 v = {0.f, 0.f, 0.f, 0.f};
            if ((unsigned)x < 56u && (unsigned)y < 56u) v = fb[y*56 + x];
            tp[lane] = v;
            int idx2 = 64 + lane;
            if (idx2 < 81) {
                int r2 = idx2 / 9, c2 = idx2 - r2*9;
                int y2 = ybase + r2, x2 = xbase + c2;
                float4 v2 = {0.f, 0.f, 0.f, 0.f};
                if ((unsigned)x2 < 56u && (unsigned)y2 < 56u) v2 = fb[y2*56 + x2];
                tp[idx2] = v2;
            }
        }
        __syncthreads();

        float4 f00 = tp[j*9 + i];
        float4 f10 = tp[j*9 + i + 1];
        float4 f01 = tp[j*9 + 9 + i];
        float4 f11 = tp[j*9 + 9 + i + 1];
        float4 v;
        v.x = wy0*(wx0*f00.x + wx1*f10.x) + wy1*(wx0*f01.x + wx1*f11.x);
        v.y = wy0*(wx0*f00.y + wx1*f10.y) + wy1*(wx0*f01.y + wx1*f11.y);
        v.z = wy0*(wx0*f00.z + wx1*f10.z) + wy1*(wx0*f01.z + wx1*f11.z);
        v.w = wy0*(wx0*f00.w + wx1*f10.w) + wy1*(wx0*f01.w + wx1*f11.w);
        // interleaved patch layout: stored col 256 + ij*4 + c  (bhw1 permuted to match)
        ushort4 o;
        o.x = f2bf(v.x); o.y = f2bf(v.y); o.z = f2bf(v.z); o.w = f2bf(v.w);
        *(ushort4*)(C + m*512 + 256 + ij*4) = o;
    }
}

// ---------------- g5 + avgpool: 32->64, 14->7, s2; atomic pool into gc ----------------
__global__ __launch_bounds__(256) void g5_k(
    const float* __restrict__ g4o, const float* __restrict__ w5,
    const float* __restrict__ b5, float* __restrict__ gc)
{
    int idx = blockIdx.x*256 + threadIdx.x;      // 196 blocks, exact
    int co = idx & 63;
    int t = idx >> 6;
    int b = t / 49, px = t - b*49;
    int ho = px / 7, wo = px - ho*7;
    const float* src = g4o + (size_t)b*6272;
    const float* wp = w5 + co*288;
    float acc = b5[co];
    for (int ci = 0; ci < 32; ++ci) {
        #pragma unroll
        for (int kh = 0; kh < 3; ++kh) {
            int hi = ho*2 - 1 + kh;
            if ((unsigned)hi >= 14u) continue;
            #pragma unroll
            for (int kw = 0; kw < 3; ++kw) {
                int wi = wo*2 - 1 + kw;
                if ((unsigned)wi >= 14u) continue;
                acc = fmaf(src[(hi*14 + wi)*32 + ci], wp[ci*9 + kh*3 + kw], acc);
            }
        }
    }
    atomicAdd(&gc[b*64 + co], gelu_t(acc) * (1.0f/49.0f));
}

// ---------------- hgc: effective head bias  hgc[b][n] = hb1[n] + sum_c gc[b,c]*hw1[n,512+c] ----------------
__global__ __launch_bounds__(256) void hgc_k(
    const float* __restrict__ gc, const float* __restrict__ hw1,
    const float* __restrict__ hb1, float* __restrict__ hgc)
{
    int idx = blockIdx.x*256 + threadIdx.x;   // 32 blocks = 8192
    int b = idx >> 9, n = idx & 511;
    const float* g = gc + b*64;
    const float* w = hw1 + (size_t)n*576 + 512;
    float s = hb1[n];
    #pragma unroll
    for (int c = 0; c < 64; ++c) s = fmaf(g[c], w[c], s);
    hgc[idx] = s;
}

// ---------------- weight conversions (bhw1 col-permuted for k in [256,512)) + out init + gc zero ----------------
__global__ void cvtall_k(const float* __restrict__ lw1, const float* __restrict__ lw2,
                         const float* __restrict__ hw1, unsigned short* __restrict__ blw1,
                         unsigned short* __restrict__ blw2, unsigned short* __restrict__ bhw1,
                         float* __restrict__ out, const float* __restrict__ b2,
                         float* __restrict__ gc){
    int i = blockIdx.x*blockDim.x + threadIdx.x;
    if (i < M_TOT) out[i] = b2[0];
    if (i < 1024) gc[i] = 0.f;
    if (i < 256*64) {
        int r = i >> 6, c = i & 63;
        blw1[i] = (c < 48) ? f2bf(lw1[r*48 + c]) : 0;
        return;
    }
    int j = i - 256*64;
    if (j < 256*256) { blw2[j] = f2bf(lw2[j]); return; }
    j -= 256*256;
    if (j < 512*576) {
        int n = j / 576, k = j - n*576;
        int src_k = k;
        if (k >= 256 && k < 512) {
            int s = k - 256;
            src_k = 256 + (s & 3)*64 + (s >> 2);   // stored ij*4+c  <-  semantic c*64+ij
        }
        bhw1[j] = f2bf(hw1[(size_t)n*576 + src_k]);
    }
}

// ================= mlp12: embed(shared) + mlp1 + mlp2 -> fused cols 0..255, M-strip 128 =================
// pe computed ONCE into LDS (no 4x redundant sinf); gemm2 B direct from global (L2-hot).
__global__ __launch_bounds__(512) void mlp12_k(
    const float* __restrict__ points,
    const unsigned short* __restrict__ W1, const float* __restrict__ b1,
    const unsigned short* __restrict__ W2, const float* __restrict__ b2,
    unsigned short* __restrict__ C)
{
    __shared__ unsigned short Pe[128*64];    // 16 KB, swizzled (phys chunk = seg ^ (row&7))
    __shared__ unsigned short Hd[128*256];   // 64 KB
    int tid = threadIdx.x;
    int wv = tid >> 6, lane = tid & 63;
    int q = lane >> 4, lr = lane & 15;
    int mi = wv >> 2, ni = wv & 3;
    size_t m0 = (size_t)blockIdx.x * 128;

    // ---- embed -> Pe (each chunk computed once) ----
    #pragma unroll
    for (int it = 0; it < 2; ++it) {
        int idx = it*512 + tid;
        int row = idx >> 3, seg = idx & 7;
        size_t m = m0 + row;
        float px = points[m*2], py = points[m*2+1];
        union { s8v v; unsigned short u[8]; } pk;
        #pragma unroll
        for (int j = 0; j < 8; ++j) {
            int k = seg*8 + j;
            unsigned short val = 0;
            if (k < 48) {
                int i2 = k >> 2, rr = k & 3;
                float f = (float)(1 << i2);
                float p = (rr & 1) ? py : px;
                float s = f * p;
                val = f2bf((rr < 2) ? __sinf(s) : __cosf(s));
            }
            pk.u[j] = val;
        }
        *(s8v*)(Pe + (row*8 + (seg ^ (row & 7)))*8) = pk.v;
    }
    __syncthreads();

    // ---- gemm1: hid = gelu(pe @ lw1^T + b1), K=64, A from Pe ----
    f4v acc1[4][4];
    #pragma unroll
    for (int i = 0; i < 4; ++i)
        #pragma unroll
        for (int j = 0; j < 4; ++j) acc1[i][j] = (f4v){0.f,0.f,0.f,0.f};

    #pragma unroll
    for (int kb = 0; kb < 2; ++kb) {
        int seg = kb*4 + q;
        s8v a[4], b[4];
        #pragma unroll
        for (int t = 0; t < 4; ++t) {
            int row = mi*64 + t*16 + lr;
            a[t] = *(const s8v*)(Pe + (row*8 + (seg ^ (row & 7)))*8);
        }
        #pragma unroll
        for (int t = 0; t < 4; ++t) {
            int n = ni*64 + t*16 + lr;
            b[t] = *(const s8v*)(W1 + n*64 + seg*8);
        }
        #pragma unroll
        for (int mt = 0; mt < 4; ++mt)
            #pragma unroll
            for (int nt = 0; nt < 4; ++nt)
                acc1[mt][nt] = __builtin_amdgcn_mfma_f32_16x16x32_bf16(a[mt], b[nt], acc1[mt][nt], 0, 0, 0);
    }
    {
        float b1v[4];
        #pragma unroll
        for (int nt = 0; nt < 4; ++nt) b1v[nt] = b1[ni*64 + nt*16 + lr];
        #pragma unroll
        for (int mt = 0; mt < 4; ++mt)
            #pragma unroll
            for (int r4 = 0; r4 < 4; ++r4) {
                int row = mi*64 + mt*16 + q*4 + r4;
                #pragma unroll
                for (int nt = 0; nt < 4; ++nt) {
                    int col = ni*64 + nt*16 + lr;
                    float v = gelu_t(acc1[mt][nt][r4] + b1v[nt]);
                    int p = (col >> 3) ^ (row & 7);
                    Hd[(row*32 + p)*8 + (col & 7)] = f2bf(v);
                }
            }
    }
    __syncthreads();

    // ---- gemm2: pf = hid @ lw2^T + b2, A from Hd, B direct from global ----
    f4v acc2[4][4];
    #pragma unroll
    for (int i = 0; i < 4; ++i)
        #pragma unroll
        for (int j = 0; j < 4; ++j) acc2[i][j] = (f4v){0.f,0.f,0.f,0.f};

    #pragma unroll 2
    for (int kt = 0; kt < 8; ++kt) {
        s8v a[4], b[4];
        #pragma unroll
        for (int t = 0; t < 4; ++t) {
            int n = ni*64 + t*16 + lr;
            b[t] = *(const s8v*)(W2 + (size_t)n*256 + kt*32 + q*8);
        }
        #pragma unroll
        for (int t = 0; t < 4; ++t) {
            int row = mi*64 + t*16 + lr;
            int p = (kt*4 + q) ^ (row & 7);
            a[t] = *(const s8v*)(Hd + (row*32 + p)*8);
        }
        #pragma unroll
        for (int mt = 0; mt < 4; ++mt)
            #pragma unroll
            for (int nt = 0; nt < 4; ++nt)
                acc2[mt][nt] = __builtin_amdgcn_mfma_f32_16x16x32_bf16(a[mt], b[nt], acc2[mt][nt], 0, 0, 0);
    }
    {
        float b2v[4];
        #pragma unroll
        for (int nt = 0; nt < 4; ++nt) b2v[nt] = b2[ni*64 + nt*16 + lr];
        #pragma unroll
        for (int mt = 0; mt < 4; ++mt)
            #pragma unroll
            for (int r4 = 0; r4 < 4; ++r4) {
                size_t m = m0 + mi*64 + mt*16 + q*4 + r4;
                #pragma unroll
                for (int nt = 0; nt < 4; ++nt) {
                    int n = ni*64 + nt*16 + lr;
                    C[m*512 + n] = f2bf(acc2[mt][nt][r4] + b2v[nt]);
                }
            }
    }
}

// ================= head: direct-register GEMM, no LDS, no K-loop barriers =================
// LDS staging bought nothing: each wave reads DISJOINT B rows (same L2 bytes
// either way) and the LDS round-trip (64KB reads + 40KB writes per block-K-step
// vs 155cy of MFMA) was the measured 4:1 bottleneck (MfmaUtil 22%). Both
// operands now load global->register in exact MFMA fragment layout (16 rows x
// 64B per instr = fully line-coalesced). W (590KB) is L2-resident; A streams
// once from HBM. Full K unroll folds offsets into the 13-bit imm; compiler
// pipelines the 128 independent loads via counted vmcnt. 4 blocks/CU.
__global__ __launch_bounds__(256, 4) void gemm_hd_k(
    const unsigned short* __restrict__ A,
    const unsigned short* __restrict__ W,
    const float* __restrict__ hgc, const float* __restrict__ w2,
    float* __restrict__ out)
{
    __shared__ float red[4*64];   // 1 KB epilogue scratch only
    int tid = threadIdx.x;
    int wv = tid >> 6, lane = tid & 63;
    int q = lane >> 4, lr = lane & 15;
    int nq = wv * 64;
    size_t m0 = (size_t)blockIdx.x * 64;
    int nbase = blockIdx.y * 256;
    int bimg = (int)(m0 >> 12);              // image index, uniform per block

    // per-lane fragment base pointers (k-offset folds into imm offset)
    const unsigned short* aP[4];
    const unsigned short* bP[4];
    #pragma unroll
    for (int t = 0; t < 4; ++t) {
        aP[t] = A + (m0 + t*16 + lr)*512 + q*8;
        bP[t] = W + (size_t)(nbase + nq + t*16 + lr)*576 + q*8;
    }

    f4v acc[4][4];
    #pragma unroll
    for (int i = 0; i < 4; ++i)
        #pragma unroll
        for (int j = 0; j < 4; ++j) acc[i][j] = (f4v){0.f,0.f,0.f,0.f};

    #pragma unroll
    for (int k0 = 0; k0 < 512; k0 += 32) {
        s8v a[4], b[4];
        #pragma unroll
        for (int t = 0; t < 4; ++t) a[t] = *(const s8v*)(aP[t] + k0);
        #pragma unroll
        for (int t = 0; t < 4; ++t) b[t] = *(const s8v*)(bP[t] + k0);
        #pragma unroll
        for (int mt = 0; mt < 4; ++mt)
            #pragma unroll
            for (int nt = 0; nt < 4; ++nt)
                acc[mt][nt] = __builtin_amdgcn_mfma_f32_16x16x32_bf16(a[mt], b[nt], acc[mt][nt], 0, 0, 0);
    }

    float bv[4], w2v[4];
    #pragma unroll
    for (int nt = 0; nt < 4; ++nt) {
        int n = nbase + nq + nt*16 + lr;
        bv[nt] = hgc[bimg*512 + n];
        w2v[nt] = w2[n];
    }
    #pragma unroll
    for (int mt = 0; mt < 4; ++mt)
        #pragma unroll
        for (int r4 = 0; r4 < 4; ++r4) {
            int ml = mt*16 + q*4 + r4;
            float s = 0.f;
            #pragma unroll
            for (int nt = 0; nt < 4; ++nt)
                s += gelu_t(acc[mt][nt][r4] + bv[nt]) * w2v[nt];
            #pragma unroll
            for (int off = 8; off > 0; off >>= 1) s += __shfl_down(s, off, 16);
            if (lr == 0) red[wv*64 + ml] = s;
        }
    __syncthreads();
    if (tid < 64) {
        float t = red[tid] + red[64 + tid] + red[128 + tid] + red[192 + tid];
        atomicAdd(&out[m0 + tid], t);
    }
}

extern "C" void kernel_launch(void* const* d_in, const int* in_sizes, int n_in,
                              void* d_out, int out_size, void* d_ws, size_t ws_size,
                              hipStream_t stream) {
    const float* points = (const float*)d_in[0];
    const float* images = (const float*)d_in[1];
    const float* pw1 = (const float*)d_in[2];  const float* pb1 = (const float*)d_in[3];
    const float* pw2 = (const float*)d_in[4];  const float* pb2 = (const float*)d_in[5];
    const float* pw3 = (const float*)d_in[6];  const float* pb3 = (const float*)d_in[7];
    const float* gw1 = (const float*)d_in[8];  const float* gb1 = (const float*)d_in[9];
    const float* gw2 = (const float*)d_in[10]; const float* gb2 = (const float*)d_in[11];
    const float* gw3 = (const float*)d_in[12]; const float* gb3 = (const float*)d_in[13];
    const float* gw4 = (const float*)d_in[14]; const float* gb4 = (const float*)d_in[15];
    const float* gw5 = (const float*)d_in[16]; const float* gb5 = (const float*)d_in[17];
    const float* lw1 = (const float*)d_in[18]; const float* lb1 = (const float*)d_in[19];
    const float* lw2 = (const float*)d_in[20]; const float* lb2 = (const float*)d_in[21];
    const float* hw1 = (const float*)d_in[22]; const float* hb1 = (const float*)d_in[23];
    const float* hw2 = (const float*)d_in[24]; const float* hb2 = (const float*)d_in[25];
    float* out = (float*)d_out;

    // ---- workspace layout ----
    char* base = (char*)d_ws;
    unsigned short* fused_b = (unsigned short*)base;                       // M*512 bf16 = 67 MB
    float4* fmap4 = (float4*)(fused_b + (size_t)M_TOT*512);                // 16*3136 float4
    float* g3   = (float*)(fmap4 + (size_t)16*3136);                       // 16*16*784 (OUT of alias region)
    float* g4o  = g3 + (size_t)16*16*784;                                  // 16*196*32 (OUT of alias region)
    float* gc   = g4o + (size_t)16*32*196;                                 // 1024
    float* hgc  = gc + 1024;                                               // 16*512
    unsigned short* blw1 = (unsigned short*)(hgc + 16*512);                // 256*64
    unsigned short* blw2 = blw1 + 256*64;                                  // 256*256
    unsigned short* bhw1 = blw2 + 256*256;                                 // 512*576 (col-permuted)
    // conv temps f1,f2,g1,g2 alias inside fused region (dead before k4 writes fused):
    float* ct = (float*)base;
    float* f1 = ct;
    float* f2 = f1 + (size_t)16*16*112*112;
    float* g1 = f2 + (size_t)16*32*56*56;
    float* g2 = g1 + (size_t)16*4*112*112;

    cvtall_k<<<1472, 256, 0, stream>>>(lw1, lw2, hw1, blw1, blw2, bhw1, out, hb2, gc);
    conv_dual_k<<<dim3(7,7,16), 256, 0, stream>>>(images, pw1, pb1, gw1, gb1, f1, g1);
    conv_pg2_k<<<dim3(4,4,48), 256, 0, stream>>>(f1, pw2, pb2, f2, g1, gw2, gb2, g2);
    conv_pg3_k<<<dim3(13,1,32), 256, 0, stream>>>(f2, pw3, pb3, fmap4, g2, gw3, gb3, g3);
    // K4: g4 + patch fill (fill depends only on pg3; runs at full-machine parallelism)
    k4_k<<<392 + 16384, 256, 0, stream>>>(g3, gw4, gb4, g4o, fmap4, points, fused_b);
    g5_k<<<196, 256, 0, stream>>>(g4o, gw5, gb5, gc);   // includes avgpool via atomics
    hgc_k<<<32, 256, 0, stream>>>(gc, hw1, hb1, hgc);   // fold gc into head bias (fp32)
    // mlp12: pure GEMM now (pe shared in LDS), writes fused cols 0..255
    mlp12_k<<<M_TOT/128, 512, 0, stream>>>(points, blw1, lb1, blw2, lb2, fused_b);
    gemm_hd_k<<<dim3(M_TOT/64, 2), 256, 0, stream>>>(fused_b, bhw1, hgc, hw2, out);
}

// Round 5
// 392.085 us; speedup vs baseline: 1.1842x; 1.1842x over previous
//
#include <hip/hip_runtime.h>
#include <math.h>

#define BB 16
#define NN 4096
#define M_TOT (BB*NN)   // 65536 points

typedef __attribute__((ext_vector_type(8))) short s8v;   // 8 bf16 = 4 VGPRs
typedef __attribute__((ext_vector_type(4))) float f4v;

// exact tanh-GELU via sigmoid identity: 0.5x(1+tanh(z)) = x * sigmoid(2z)
__device__ __forceinline__ float gelu_t(float x){
    float u = 1.5957691216057308f * x * (1.0f + 0.044715f*x*x);
    return x / (1.0f + __expf(-u));
}

__device__ __forceinline__ unsigned short f2bf(float f){
    unsigned int u = __float_as_uint(f);
    u += 0x7fffu + ((u >> 16) & 1u);
    return (unsigned short)(u >> 16);
}

#define GLL(src, dst) __builtin_amdgcn_global_load_lds( \
    (const __attribute__((address_space(1))) void*)(src), \
    (__attribute__((address_space(3))) void*)(dst), 16, 0, 0)

// ---------------- chunked-staging conv device fn: CHUNK channels per barrier ----------------
template<int CIN, int COUT, int STRIDE, int CHUNK>
__device__ __forceinline__ void conv_dev2(
    const float* __restrict__ in, const float* __restrict__ w,
    const float* __restrict__ bias, float* __restrict__ out,
    int Hin, int Win, int Hout, int Wout, int bx, int by, int b, float* tile)
{
    constexpr int IW = 15*STRIDE + 3;
    constexpr int IH = IW;
    constexpr int PITCH = IW + 1;
    int tid = threadIdx.x;
    int tx = tid & 15, ty = tid >> 4;
    int wo = bx*16 + tx;
    int ho = by*16 + ty;
    int win0 = bx*16*STRIDE - 1;
    int hin0 = by*16*STRIDE - 1;
    bool valid = (wo < Wout) && (ho < Hout);

    float acc[COUT];
    #pragma unroll
    for (int co = 0; co < COUT; ++co) acc[co] = bias[co];

    const float* ib = in + (size_t)(b*CIN)*Hin*Win;
    for (int ci0 = 0; ci0 < CIN; ci0 += CHUNK) {
        __syncthreads();
        for (int idx = tid; idx < CHUNK*IH*IW; idx += 256) {
            int c = idx / (IH*IW), rem = idx - c*(IH*IW);
            int r = rem / IW, cc = rem - r*IW;
            int hi = hin0 + r, wi = win0 + cc;
            float v = 0.f;
            if ((unsigned)hi < (unsigned)Hin && (unsigned)wi < (unsigned)Win)
                v = ib[(size_t)(ci0 + c)*Hin*Win + hi*Win + wi];
            tile[c*IH*PITCH + r*PITCH + cc] = v;
        }
        __syncthreads();
        for (int ci = 0; ci < CHUNK; ++ci) {
            float vv[9];
            const float* tb = tile + ci*IH*PITCH;
            #pragma unroll
            for (int kh = 0; kh < 3; ++kh)
                #pragma unroll
                for (int kw = 0; kw < 3; ++kw)
                    vv[kh*3+kw] = tb[(ty*STRIDE + kh)*PITCH + tx*STRIDE + kw];
            const float* wc = w + (ci0 + ci)*9;
            #pragma unroll
            for (int co = 0; co < COUT; ++co) {
                const float* wp = wc + co*CIN*9;
                #pragma unroll
                for (int k = 0; k < 9; ++k)
                    acc[co] = fmaf(vv[k], wp[k], acc[co]);
            }
        }
    }
    if (valid) {
        size_t obase = ((size_t)b*COUT)*Hout*Wout + (size_t)ho*Wout + wo;
        #pragma unroll
        for (int co = 0; co < COUT; ++co)
            out[obase + (size_t)co*Hout*Wout] = gelu_t(acc[co]);
    }
}

// ---------------- dual conv1: plane (16ch) + global (4ch), all 3 ci staged once ----------------
__global__ __launch_bounds__(256) void conv_dual_k(
    const float* __restrict__ in,
    const float* __restrict__ wA, const float* __restrict__ bA,
    const float* __restrict__ wB, const float* __restrict__ bB,
    float* __restrict__ outA, float* __restrict__ outB)
{
    __shared__ float tile[3*33*34];   // 13.5 KB
    const int Hin = 224, Win = 224, Hout = 112, Wout = 112;
    int tid = threadIdx.x;
    int tx = tid & 15, ty = tid >> 4;
    int b = blockIdx.z;
    int wo = blockIdx.x*16 + tx;
    int ho = blockIdx.y*16 + ty;
    int win0 = blockIdx.x*32 - 1;
    int hin0 = blockIdx.y*32 - 1;

    const float* ib = in + (size_t)(b*3)*Hin*Win;
    for (int idx = tid; idx < 3*1089; idx += 256) {
        int c = idx / 1089, rem = idx - c*1089;
        int r = rem / 33, cc = rem - r*33;
        int hi = hin0 + r, wi = win0 + cc;
        float v = 0.f;
        if ((unsigned)hi < (unsigned)Hin && (unsigned)wi < (unsigned)Win)
            v = ib[(size_t)c*Hin*Win + hi*Win + wi];
        tile[c*33*34 + r*34 + cc] = v;
    }
    __syncthreads();

    float accA[16], accB[4];
    #pragma unroll
    for (int co = 0; co < 16; ++co) accA[co] = bA[co];
    #pragma unroll
    for (int co = 0; co < 4; ++co) accB[co] = bB[co];

    #pragma unroll
    for (int ci = 0; ci < 3; ++ci) {
        float vv[9];
        const float* tb = tile + ci*33*34;
        #pragma unroll
        for (int kh = 0; kh < 3; ++kh)
            #pragma unroll
            for (int kw = 0; kw < 3; ++kw)
                vv[kh*3+kw] = tb[(ty*2 + kh)*34 + tx*2 + kw];
        #pragma unroll
        for (int co = 0; co < 16; ++co) {
            const float* wp = wA + co*27 + ci*9;
            #pragma unroll
            for (int k = 0; k < 9; ++k) accA[co] = fmaf(vv[k], wp[k], accA[co]);
        }
        #pragma unroll
        for (int co = 0; co < 4; ++co) {
            const float* wp = wB + co*27 + ci*9;
            #pragma unroll
            for (int k = 0; k < 9; ++k) accB[co] = fmaf(vv[k], wp[k], accB[co]);
        }
    }
    size_t px = (size_t)ho*Wout + wo;
    #pragma unroll
    for (int co = 0; co < 16; ++co)
        outA[((size_t)(b*16 + co))*Hout*Wout + px] = gelu_t(accA[co]);
    #pragma unroll
    for (int co = 0; co < 4; ++co)
        outB[((size_t)(b*4 + co))*Hout*Wout + px] = gelu_t(accB[co]);
}

// ---------------- layer-2 convs: plane p2 (16->32, split co 2x16) + global g2 (4->8) ----------------
__global__ __launch_bounds__(256) void conv_pg2_k(
    const float* __restrict__ f1, const float* __restrict__ pw2, const float* __restrict__ pb2, float* __restrict__ f2,
    const float* __restrict__ g1, const float* __restrict__ gw2, const float* __restrict__ gb2, float* __restrict__ g2)
{
    __shared__ float tile[8*33*34];   // 35.9 KB
    int z = blockIdx.z;
    if (z < 32) {
        int b = z >> 1, half = z & 1;
        conv_dev2<16,16,2,8>(f1 + (size_t)b*16*12544, pw2 + half*2304, pb2 + half*16,
                             f2 + ((size_t)(b*32 + half*16))*3136,
                             112,112, 56,56, blockIdx.x, blockIdx.y, 0, tile);
    } else {
        conv_dev2<4,8,2,4>(g1, gw2, gb2, g2, 112,112, 56,56, blockIdx.x, blockIdx.y, z-32, tile);
    }
}

// ---------------- layer-3: plane p3 DIRECT (32->4, NHWC out) + global g3 (8->16, LDS) ----------------
__global__ __launch_bounds__(256) void conv_pg3_k(
    const float* __restrict__ f2, const float* __restrict__ pw3, const float* __restrict__ pb3, float4* __restrict__ fmap4,
    const float* __restrict__ g2, const float* __restrict__ gw3, const float* __restrict__ gb3, float* __restrict__ g3)
{
    __shared__ float tile[8*33*34];
    int z = blockIdx.z;
    if (z < 16) {
        int b = z;
        int idx = blockIdx.x*256 + threadIdx.x;
        if (idx >= 3136) return;
        int ho = idx / 56, wo = idx - ho*56;
        const float* ib = f2 + (size_t)b*32*3136;
        float acc[4];
        #pragma unroll
        for (int co = 0; co < 4; ++co) acc[co] = pb3[co];
        for (int ci = 0; ci < 32; ++ci) {
            const float* ic = ib + (size_t)ci*3136;
            #pragma unroll
            for (int kh = 0; kh < 3; ++kh) {
                int hi = ho - 1 + kh;
                if ((unsigned)hi >= 56u) continue;
                #pragma unroll
                for (int kw = 0; kw < 3; ++kw) {
                    int wi = wo - 1 + kw;
                    if ((unsigned)wi >= 56u) continue;
                    float v = ic[hi*56 + wi];
                    int wofs = ci*9 + kh*3 + kw;
                    #pragma unroll
                    for (int co = 0; co < 4; ++co)
                        acc[co] = fmaf(v, pw3[co*288 + wofs], acc[co]);
                }
            }
        }
        float4 o;
        o.x = gelu_t(acc[0]); o.y = gelu_t(acc[1]);
        o.z = gelu_t(acc[2]); o.w = gelu_t(acc[3]);
        fmap4[(size_t)b*3136 + idx] = o;
    } else {
        if (blockIdx.x >= 4) return;
        int bx = blockIdx.x & 1, by = blockIdx.x >> 1;
        conv_dev2<8,16,2,8>(g2, gw3, gb3, g3, 56,56, 28,28, bx, by, z-16, tile);
    }
}

// ================= K4: g4 (392 blocks) + patch fill (16384 blocks) =================
// Patch fill: tap spacing is exactly 1.0 pixel -> all 64 taps of a point share
// one fractional weight pair and lie on an integer 9x9 window. Per wave:
// cooperatively load the 9x9 float4 window into LDS (zero-fill OOB == validity
// masking), then each lane blends its 4 corners with shared wx/wy weights.
__global__ __launch_bounds__(256) void k4_k(
    const float* __restrict__ g3, const float* __restrict__ w4,
    const float* __restrict__ b4, float* __restrict__ g4o,
    const float4* __restrict__ fmap4, const float* __restrict__ points,
    unsigned short* __restrict__ C)
{
    __shared__ float4 pt[4*81];   // 5.2 KB: 4 waves x 9x9 window
    int bid = blockIdx.x;
    int tid = threadIdx.x;
    if (bid < 392) {
        int idx = bid*256 + tid;
        int co = idx & 31;
        int t = idx >> 5;
        int b = t / 196, px = t - b*196;
        int ho = px / 14, wo = px - ho*14;
        const float* src = g3 + (size_t)b*16*784;
        const float* wp = w4 + co*144;
        float acc = b4[co];
        for (int ci = 0; ci < 16; ++ci) {
            #pragma unroll
            for (int kh = 0; kh < 3; ++kh) {
                int hi = ho*2 - 1 + kh;
                if ((unsigned)hi >= 28u) continue;
                #pragma unroll
                for (int kw = 0; kw < 3; ++kw) {
                    int wi = wo*2 - 1 + kw;
                    if ((unsigned)wi >= 28u) continue;
                    acc = fmaf(src[ci*784 + hi*28 + wi], wp[ci*9 + kh*3 + kw], acc);
                }
            }
        }
        g4o[(size_t)b*6272 + px*32 + co] = gelu_t(acc);
    } else {
        int task = (bid - 392)*256 + tid;     // M*64 tasks, exact
        int wv = tid >> 6, lane = tid & 63;
        size_t m = (size_t)(task >> 6);       // wave-uniform point index
        int ij = task & 63;
        int i = ij >> 3, j = ij & 7;          // i: x tap index, j: y tap index
        int b = (int)(m >> 12);
        float px = points[m*2], py = points[m*2+1];
        // ix = 55*px + (i-3.5): integer tap spacing -> shared fractional weights
        float X = fmaf(px, 55.f, -3.5f);      // = ix at i=0
        float Y = fmaf(py, 55.f, -3.5f);
        float xbf = floorf(X), ybf = floorf(Y);
        int xbase = (int)xbf, ybase = (int)ybf;
        float wx1 = X - xbf, wx0 = 1.f - wx1;
        float wy1 = Y - ybf, wy0 = 1.f - wy1;
        const float4* fb = fmap4 + (size_t)b*3136;
        float4* tp = pt + wv*81;

        // cooperative load: 81 float4 (rows = y, cols = x), zero-fill OOB
        {
            int r = lane / 9, c = lane - r*9;
            int y = ybase + r, x = xbase + c;
            float4 v = {0.f, 0.f, 0.f, 0.f};
            if ((unsigned)x < 56u && (unsigned)y < 56u) v = fb[y*56 + x];
            tp[lane] = v;
            int idx2 = 64 + lane;
            if (idx2 < 81) {
                int r2 = idx2 / 9, c2 = idx2 - r2*9;
                int y2 = ybase + r2, x2 = xbase + c2;
                float4 v2 = {0.f, 0.f, 0.f, 0.f};
                if ((unsigned)x2 < 56u && (unsigned)y2 < 56u) v2 = fb[y2*56 + x2];
                tp[idx2] = v2;
            }
        }
        __syncthreads();

        float4 f00 = tp[j*9 + i];
        float4 f10 = tp[j*9 + i + 1];
        float4 f01 = tp[j*9 + 9 + i];
        float4 f11 = tp[j*9 + 9 + i + 1];
        float4 v;
        v.x = wy0*(wx0*f00.x + wx1*f10.x) + wy1*(wx0*f01.x + wx1*f11.x);
        v.y = wy0*(wx0*f00.y + wx1*f10.y) + wy1*(wx0*f01.y + wx1*f11.y);
        v.z = wy0*(wx0*f00.z + wx1*f10.z) + wy1*(wx0*f01.z + wx1*f11.z);
        v.w = wy0*(wx0*f00.w + wx1*f10.w) + wy1*(wx0*f01.w + wx1*f11.w);
        // interleaved patch layout: stored col 256 + ij*4 + c  (bhw1 permuted to match)
        ushort4 o;
        o.x = f2bf(v.x); o.y = f2bf(v.y); o.z = f2bf(v.z); o.w = f2bf(v.w);
        *(ushort4*)(C + m*512 + 256 + ij*4) = o;
    }
}

// ---------------- g5 + avgpool: 32->64, 14->7, s2; atomic pool into gc ----------------
__global__ __launch_bounds__(256) void g5_k(
    const float* __restrict__ g4o, const float* __restrict__ w5,
    const float* __restrict__ b5, float* __restrict__ gc)
{
    int idx = blockIdx.x*256 + threadIdx.x;      // 196 blocks, exact
    int co = idx & 63;
    int t = idx >> 6;
    int b = t / 49, px = t - b*49;
    int ho = px / 7, wo = px - ho*7;
    const float* src = g4o + (size_t)b*6272;
    const float* wp = w5 + co*288;
    float acc = b5[co];
    for (int ci = 0; ci < 32; ++ci) {
        #pragma unroll
        for (int kh = 0; kh < 3; ++kh) {
            int hi = ho*2 - 1 + kh;
            if ((unsigned)hi >= 14u) continue;
            #pragma unroll
            for (int kw = 0; kw < 3; ++kw) {
                int wi = wo*2 - 1 + kw;
                if ((unsigned)wi >= 14u) continue;
                acc = fmaf(src[(hi*14 + wi)*32 + ci], wp[ci*9 + kh*3 + kw], acc);
            }
        }
    }
    atomicAdd(&gc[b*64 + co], gelu_t(acc) * (1.0f/49.0f));
}

// ---------------- hgc: effective head bias  hgc[b][n] = hb1[n] + sum_c gc[b,c]*hw1[n,512+c] ----------------
__global__ __launch_bounds__(256) void hgc_k(
    const float* __restrict__ gc, const float* __restrict__ hw1,
    const float* __restrict__ hb1, float* __restrict__ hgc)
{
    int idx = blockIdx.x*256 + threadIdx.x;   // 32 blocks = 8192
    int b = idx >> 9, n = idx & 511;
    const float* g = gc + b*64;
    const float* w = hw1 + (size_t)n*576 + 512;
    float s = hb1[n];
    #pragma unroll
    for (int c = 0; c < 64; ++c) s = fmaf(g[c], w[c], s);
    hgc[idx] = s;
}

// ---------------- weight conversions (bhw1 col-permuted for k in [256,512)) + out init + gc zero ----------------
__global__ void cvtall_k(const float* __restrict__ lw1, const float* __restrict__ lw2,
                         const float* __restrict__ hw1, unsigned short* __restrict__ blw1,
                         unsigned short* __restrict__ blw2, unsigned short* __restrict__ bhw1,
                         float* __restrict__ out, const float* __restrict__ b2,
                         float* __restrict__ gc){
    int i = blockIdx.x*blockDim.x + threadIdx.x;
    if (i < M_TOT) out[i] = b2[0];
    if (i < 1024) gc[i] = 0.f;
    if (i < 256*64) {
        int r = i >> 6, c = i & 63;
        blw1[i] = (c < 48) ? f2bf(lw1[r*48 + c]) : 0;
        return;
    }
    int j = i - 256*64;
    if (j < 256*256) { blw2[j] = f2bf(lw2[j]); return; }
    j -= 256*256;
    if (j < 512*576) {
        int n = j / 576, k = j - n*576;
        int src_k = k;
        if (k >= 256 && k < 512) {
            int s = k - 256;
            src_k = 256 + (s & 3)*64 + (s >> 2);   // stored ij*4+c  <-  semantic c*64+ij
        }
        bhw1[j] = f2bf(hw1[(size_t)n*576 + src_k]);
    }
}

// ================= mlp12: embed(shared) + mlp1 + mlp2 -> fused cols 0..255, M-strip 128 =================
// pe computed ONCE into LDS (no 4x redundant sinf); gemm2 B direct from global (L2-hot).
__global__ __launch_bounds__(512) void mlp12_k(
    const float* __restrict__ points,
    const unsigned short* __restrict__ W1, const float* __restrict__ b1,
    const unsigned short* __restrict__ W2, const float* __restrict__ b2,
    unsigned short* __restrict__ C)
{
    __shared__ unsigned short Pe[128*64];    // 16 KB, swizzled (phys chunk = seg ^ (row&7))
    __shared__ unsigned short Hd[128*256];   // 64 KB
    int tid = threadIdx.x;
    int wv = tid >> 6, lane = tid & 63;
    int q = lane >> 4, lr = lane & 15;
    int mi = wv >> 2, ni = wv & 3;
    size_t m0 = (size_t)blockIdx.x * 128;

    // ---- embed -> Pe (each chunk computed once) ----
    #pragma unroll
    for (int it = 0; it < 2; ++it) {
        int idx = it*512 + tid;
        int row = idx >> 3, seg = idx & 7;
        size_t m = m0 + row;
        float px = points[m*2], py = points[m*2+1];
        union { s8v v; unsigned short u[8]; } pk;
        #pragma unroll
        for (int j = 0; j < 8; ++j) {
            int k = seg*8 + j;
            unsigned short val = 0;
            if (k < 48) {
                int i2 = k >> 2, rr = k & 3;
                float f = (float)(1 << i2);
                float p = (rr & 1) ? py : px;
                float s = f * p;
                val = f2bf((rr < 2) ? __sinf(s) : __cosf(s));
            }
            pk.u[j] = val;
        }
        *(s8v*)(Pe + (row*8 + (seg ^ (row & 7)))*8) = pk.v;
    }
    __syncthreads();

    // ---- gemm1: hid = gelu(pe @ lw1^T + b1), K=64, A from Pe ----
    f4v acc1[4][4];
    #pragma unroll
    for (int i = 0; i < 4; ++i)
        #pragma unroll
        for (int j = 0; j < 4; ++j) acc1[i][j] = (f4v){0.f,0.f,0.f,0.f};

    #pragma unroll
    for (int kb = 0; kb < 2; ++kb) {
        int seg = kb*4 + q;
        s8v a[4], b[4];
        #pragma unroll
        for (int t = 0; t < 4; ++t) {
            int row = mi*64 + t*16 + lr;
            a[t] = *(const s8v*)(Pe + (row*8 + (seg ^ (row & 7)))*8);
        }
        #pragma unroll
        for (int t = 0; t < 4; ++t) {
            int n = ni*64 + t*16 + lr;
            b[t] = *(const s8v*)(W1 + n*64 + seg*8);
        }
        #pragma unroll
        for (int mt = 0; mt < 4; ++mt)
            #pragma unroll
            for (int nt = 0; nt < 4; ++nt)
                acc1[mt][nt] = __builtin_amdgcn_mfma_f32_16x16x32_bf16(a[mt], b[nt], acc1[mt][nt], 0, 0, 0);
    }
    {
        float b1v[4];
        #pragma unroll
        for (int nt = 0; nt < 4; ++nt) b1v[nt] = b1[ni*64 + nt*16 + lr];
        #pragma unroll
        for (int mt = 0; mt < 4; ++mt)
            #pragma unroll
            for (int r4 = 0; r4 < 4; ++r4) {
                int row = mi*64 + mt*16 + q*4 + r4;
                #pragma unroll
                for (int nt = 0; nt < 4; ++nt) {
                    int col = ni*64 + nt*16 + lr;
                    float v = gelu_t(acc1[mt][nt][r4] + b1v[nt]);
                    int p = (col >> 3) ^ (row & 7);
                    Hd[(row*32 + p)*8 + (col & 7)] = f2bf(v);
                }
            }
    }
    __syncthreads();

    // ---- gemm2: pf = hid @ lw2^T + b2, A from Hd, B direct from global ----
    f4v acc2[4][4];
    #pragma unroll
    for (int i = 0; i < 4; ++i)
        #pragma unroll
        for (int j = 0; j < 4; ++j) acc2[i][j] = (f4v){0.f,0.f,0.f,0.f};

    #pragma unroll 2
    for (int kt = 0; kt < 8; ++kt) {
        s8v a[4], b[4];
        #pragma unroll
        for (int t = 0; t < 4; ++t) {
            int n = ni*64 + t*16 + lr;
            b[t] = *(const s8v*)(W2 + (size_t)n*256 + kt*32 + q*8);
        }
        #pragma unroll
        for (int t = 0; t < 4; ++t) {
            int row = mi*64 + t*16 + lr;
            int p = (kt*4 + q) ^ (row & 7);
            a[t] = *(const s8v*)(Hd + (row*32 + p)*8);
        }
        #pragma unroll
        for (int mt = 0; mt < 4; ++mt)
            #pragma unroll
            for (int nt = 0; nt < 4; ++nt)
                acc2[mt][nt] = __builtin_amdgcn_mfma_f32_16x16x32_bf16(a[mt], b[nt], acc2[mt][nt], 0, 0, 0);
    }
    {
        float b2v[4];
        #pragma unroll
        for (int nt = 0; nt < 4; ++nt) b2v[nt] = b2[ni*64 + nt*16 + lr];
        #pragma unroll
        for (int mt = 0; mt < 4; ++mt)
            #pragma unroll
            for (int r4 = 0; r4 < 4; ++r4) {
                size_t m = m0 + mi*64 + mt*16 + q*4 + r4;
                #pragma unroll
                for (int nt = 0; nt < 4; ++nt) {
                    int n = ni*64 + nt*16 + lr;
                    C[m*512 + n] = f2bf(acc2[mt][nt][r4] + b2v[nt]);
                }
            }
    }
}

// ================= head: 256 thr, tile 128x256 (4 waves x 64x128), BK=64, K=512 =================
// R1 transport (GLL staging + XOR-swizzled LDS, single buffer) kept — R3 proved
// direct-register loads catastrophic (strided 16-line expansion at TA). Tile
// grown 64x256 -> 128x256 with 64x128/wave (acc 4x8): LDS frag bytes/MFMA
// 512->384, L2 staging traffic 656->384 MB, half the blocks. LDS 49 KB.
__global__ __launch_bounds__(256, 2) void gemm_hd_k(
    const unsigned short* __restrict__ A,
    const unsigned short* __restrict__ W,
    const float* __restrict__ hgc, const float* __restrict__ w2,
    float* __restrict__ out)
{
    __shared__ unsigned short As[128*64];    // 16 KB
    __shared__ unsigned short Bs[256*64];    // 32 KB
    __shared__ float red[4*64];              // 1 KB
    int tid = threadIdx.x;
    int wv = tid >> 6, lane = tid & 63;
    int q = lane >> 4, lr = lane & 15;
    int wm = wv >> 1, wn = wv & 1;           // 2x2 wave grid, wave tile 64x128
    size_t m0 = (size_t)blockIdx.x * 128;
    int nbase = blockIdx.y * 256;
    int bimg = (int)(m0 >> 12);              // image index, uniform per block

    const unsigned short* srcA[4]; int dA[4];
    #pragma unroll
    for (int r = 0; r < 4; ++r) {
        int f = r*256 + tid;
        int row = f >> 3, sl = (f & 7) ^ (row & 7);
        srcA[r] = A + (m0 + row)*512 + sl*8;
        dA[r] = f*8;
    }
    const unsigned short* srcB[8]; int dB[8];
    #pragma unroll
    for (int r = 0; r < 8; ++r) {
        int f = r*256 + tid;
        int row = f >> 3, sl = (f & 7) ^ (row & 7);
        srcB[r] = W + (size_t)(nbase + row)*576 + sl*8;
        dB[r] = f*8;
    }

    f4v acc[4][8];
    #pragma unroll
    for (int i = 0; i < 4; ++i)
        #pragma unroll
        for (int j = 0; j < 8; ++j) acc[i][j] = (f4v){0.f,0.f,0.f,0.f};

    for (int k0 = 0; k0 < 512; k0 += 64) {
        #pragma unroll
        for (int r = 0; r < 4; ++r) { GLL(srcA[r], As + dA[r]); srcA[r] += 64; }
        #pragma unroll
        for (int r = 0; r < 8; ++r) { GLL(srcB[r], Bs + dB[r]); srcB[r] += 64; }
        __syncthreads();
        #pragma unroll
        for (int kk = 0; kk < 2; ++kk) {
            s8v a[4], b[8];
            #pragma unroll
            for (int t = 0; t < 4; ++t) {
                int row = wm*64 + t*16 + lr;
                int ph = (kk*4 + q) ^ (row & 7);
                a[t] = *(const s8v*)(As + (row*8 + ph)*8);
            }
            #pragma unroll
            for (int t = 0; t < 8; ++t) {
                int row = wn*128 + t*16 + lr;
                int ph = (kk*4 + q) ^ (row & 7);
                b[t] = *(const s8v*)(Bs + (row*8 + ph)*8);
            }
            #pragma unroll
            for (int mt = 0; mt < 4; ++mt)
                #pragma unroll
                for (int nt = 0; nt < 8; ++nt)
                    acc[mt][nt] = __builtin_amdgcn_mfma_f32_16x16x32_bf16(a[mt], b[nt], acc[mt][nt], 0, 0, 0);
        }
        __syncthreads();
    }

    float bv[8], w2v[8];
    #pragma unroll
    for (int nt = 0; nt < 8; ++nt) {
        int n = nbase + wn*128 + nt*16 + lr;
        bv[nt] = hgc[bimg*512 + n];
        w2v[nt] = w2[n];
    }
    #pragma unroll
    for (int mt = 0; mt < 4; ++mt)
        #pragma unroll
        for (int r4 = 0; r4 < 4; ++r4) {
            int ml = mt*16 + q*4 + r4;       // row within wave's 64
            float s = 0.f;
            #pragma unroll
            for (int nt = 0; nt < 8; ++nt)
                s += gelu_t(acc[mt][nt][r4] + bv[nt]) * w2v[nt];
            #pragma unroll
            for (int off = 8; off > 0; off >>= 1) s += __shfl_down(s, off, 16);
            if (lr == 0) red[wv*64 + ml] = s;
        }
    __syncthreads();
    if (tid < 128) {
        int wmI = tid >> 6, ml = tid & 63;
        float t = red[(wmI*2)*64 + ml] + red[(wmI*2 + 1)*64 + ml];
        atomicAdd(&out[m0 + tid], t);
    }
}

extern "C" void kernel_launch(void* const* d_in, const int* in_sizes, int n_in,
                              void* d_out, int out_size, void* d_ws, size_t ws_size,
                              hipStream_t stream) {
    const float* points = (const float*)d_in[0];
    const float* images = (const float*)d_in[1];
    const float* pw1 = (const float*)d_in[2];  const float* pb1 = (const float*)d_in[3];
    const float* pw2 = (const float*)d_in[4];  const float* pb2 = (const float*)d_in[5];
    const float* pw3 = (const float*)d_in[6];  const float* pb3 = (const float*)d_in[7];
    const float* gw1 = (const float*)d_in[8];  const float* gb1 = (const float*)d_in[9];
    const float* gw2 = (const float*)d_in[10]; const float* gb2 = (const float*)d_in[11];
    const float* gw3 = (const float*)d_in[12]; const float* gb3 = (const float*)d_in[13];
    const float* gw4 = (const float*)d_in[14]; const float* gb4 = (const float*)d_in[15];
    const float* gw5 = (const float*)d_in[16]; const float* gb5 = (const float*)d_in[17];
    const float* lw1 = (const float*)d_in[18]; const float* lb1 = (const float*)d_in[19];
    const float* lw2 = (const float*)d_in[20]; const float* lb2 = (const float*)d_in[21];
    const float* hw1 = (const float*)d_in[22]; const float* hb1 = (const float*)d_in[23];
    const float* hw2 = (const float*)d_in[24]; const float* hb2 = (const float*)d_in[25];
    float* out = (float*)d_out;

    // ---- workspace layout ----
    char* base = (char*)d_ws;
    unsigned short* fused_b = (unsigned short*)base;                       // M*512 bf16 = 67 MB
    float4* fmap4 = (float4*)(fused_b + (size_t)M_TOT*512);                // 16*3136 float4
    float* g3   = (float*)(fmap4 + (size_t)16*3136);                       // 16*16*784 (OUT of alias region)
    float* g4o  = g3 + (size_t)16*16*784;                                  // 16*196*32 (OUT of alias region)
    float* gc   = g4o + (size_t)16*32*196;                                 // 1024
    float* hgc  = gc + 1024;                                               // 16*512
    unsigned short* blw1 = (unsigned short*)(hgc + 16*512);                // 256*64
    unsigned short* blw2 = blw1 + 256*64;                                  // 256*256
    unsigned short* bhw1 = blw2 + 256*256;                                 // 512*576 (col-permuted)
    // conv temps f1,f2,g1,g2 alias inside fused region (dead before k4 writes fused):
    float* ct = (float*)base;
    float* f1 = ct;
    float* f2 = f1 + (size_t)16*16*112*112;
    float* g1 = f2 + (size_t)16*32*56*56;
    float* g2 = g1 + (size_t)16*4*112*112;

    cvtall_k<<<1472, 256, 0, stream>>>(lw1, lw2, hw1, blw1, blw2, bhw1, out, hb2, gc);
    conv_dual_k<<<dim3(7,7,16), 256, 0, stream>>>(images, pw1, pb1, gw1, gb1, f1, g1);
    conv_pg2_k<<<dim3(4,4,48), 256, 0, stream>>>(f1, pw2, pb2, f2, g1, gw2, gb2, g2);
    conv_pg3_k<<<dim3(13,1,32), 256, 0, stream>>>(f2, pw3, pb3, fmap4, g2, gw3, gb3, g3);
    // K4: g4 + patch fill (fill depends only on pg3; runs at full-machine parallelism)
    k4_k<<<392 + 16384, 256, 0, stream>>>(g3, gw4, gb4, g4o, fmap4, points, fused_b);
    g5_k<<<196, 256, 0, stream>>>(g4o, gw5, gb5, gc);   // includes avgpool via atomics
    hgc_k<<<32, 256, 0, stream>>>(gc, hw1, hb1, hgc);   // fold gc into head bias (fp32)
    // mlp12: pure GEMM now (pe shared in LDS), writes fused cols 0..255
    mlp12_k<<<M_TOT/128, 512, 0, stream>>>(points, blw1, lb1, blw2, lb2, fused_b);
    gemm_hd_k<<<dim3(M_TOT/128, 2), 256, 0, stream>>>(fused_b, bhw1, hgc, hw2, out);
}

// Round 8
// 389.882 us; speedup vs baseline: 1.1908x; 1.0056x over previous
//
#include <hip/hip_runtime.h>
#include <math.h>

#define BB 16
#define NN 4096
#define M_TOT (BB*NN)   // 65536 points

typedef __attribute__((ext_vector_type(8))) short s8v;   // 8 bf16 = 4 VGPRs
typedef __attribute__((ext_vector_type(4))) float f4v;

// exact tanh-GELU via sigmoid identity: 0.5x(1+tanh(z)) = x * sigmoid(2z)
__device__ __forceinline__ float gelu_t(float x){
    float u = 1.5957691216057308f * x * (1.0f + 0.044715f*x*x);
    return x / (1.0f + __expf(-u));
}

__device__ __forceinline__ unsigned short f2bf(float f){
    unsigned int u = __float_as_uint(f);
    u += 0x7fffu + ((u >> 16) & 1u);
    return (unsigned short)(u >> 16);
}

// NOTE (R6 lesson): the 4th arg (offset) of global_load_lds is NOT a pure
// global-address offset — it also shifts the LDS destination (M0+offset
// semantics), which scrambled staging (absmax 0.95). Keep it 0; express
// k-stepping as compile-time pointer arithmetic on the global source.
#define GLL(src, dst) __builtin_amdgcn_global_load_lds( \
    (const __attribute__((address_space(1))) void*)(src), \
    (__attribute__((address_space(3))) void*)(dst), 16, 0, 0)

// ---------------- chunked-staging conv device fn: CHUNK channels per barrier ----------------
template<int CIN, int COUT, int STRIDE, int CHUNK>
__device__ __forceinline__ void conv_dev2(
    const float* __restrict__ in, const float* __restrict__ w,
    const float* __restrict__ bias, float* __restrict__ out,
    int Hin, int Win, int Hout, int Wout, int bx, int by, int b, float* tile)
{
    constexpr int IW = 15*STRIDE + 3;
    constexpr int IH = IW;
    constexpr int PITCH = IW + 1;
    int tid = threadIdx.x;
    int tx = tid & 15, ty = tid >> 4;
    int wo = bx*16 + tx;
    int ho = by*16 + ty;
    int win0 = bx*16*STRIDE - 1;
    int hin0 = by*16*STRIDE - 1;
    bool valid = (wo < Wout) && (ho < Hout);

    float acc[COUT];
    #pragma unroll
    for (int co = 0; co < COUT; ++co) acc[co] = bias[co];

    const float* ib = in + (size_t)(b*CIN)*Hin*Win;
    for (int ci0 = 0; ci0 < CIN; ci0 += CHUNK) {
        __syncthreads();
        for (int idx = tid; idx < CHUNK*IH*IW; idx += 256) {
            int c = idx / (IH*IW), rem = idx - c*(IH*IW);
            int r = rem / IW, cc = rem - r*IW;
            int hi = hin0 + r, wi = win0 + cc;
            float v = 0.f;
            if ((unsigned)hi < (unsigned)Hin && (unsigned)wi < (unsigned)Win)
                v = ib[(size_t)(ci0 + c)*Hin*Win + hi*Win + wi];
            tile[c*IH*PITCH + r*PITCH + cc] = v;
        }
        __syncthreads();
        for (int ci = 0; ci < CHUNK; ++ci) {
            float vv[9];
            const float* tb = tile + ci*IH*PITCH;
            #pragma unroll
            for (int kh = 0; kh < 3; ++kh)
                #pragma unroll
                for (int kw = 0; kw < 3; ++kw)
                    vv[kh*3+kw] = tb[(ty*STRIDE + kh)*PITCH + tx*STRIDE + kw];
            const float* wc = w + (ci0 + ci)*9;
            #pragma unroll
            for (int co = 0; co < COUT; ++co) {
                const float* wp = wc + co*CIN*9;
                #pragma unroll
                for (int k = 0; k < 9; ++k)
                    acc[co] = fmaf(vv[k], wp[k], acc[co]);
            }
        }
    }
    if (valid) {
        size_t obase = ((size_t)b*COUT)*Hout*Wout + (size_t)ho*Wout + wo;
        #pragma unroll
        for (int co = 0; co < COUT; ++co)
            out[obase + (size_t)co*Hout*Wout] = gelu_t(acc[co]);
    }
}

// ---------------- dual conv1: plane (16ch) + global (4ch), all 3 ci staged once ----------------
__global__ __launch_bounds__(256) void conv_dual_k(
    const float* __restrict__ in,
    const float* __restrict__ wA, const float* __restrict__ bA,
    const float* __restrict__ wB, const float* __restrict__ bB,
    float* __restrict__ outA, float* __restrict__ outB)
{
    __shared__ float tile[3*33*34];   // 13.5 KB
    const int Hin = 224, Win = 224, Hout = 112, Wout = 112;
    int tid = threadIdx.x;
    int tx = tid & 15, ty = tid >> 4;
    int b = blockIdx.z;
    int wo = blockIdx.x*16 + tx;
    int ho = blockIdx.y*16 + ty;
    int win0 = blockIdx.x*32 - 1;
    int hin0 = blockIdx.y*32 - 1;

    const float* ib = in + (size_t)(b*3)*Hin*Win;
    for (int idx = tid; idx < 3*1089; idx += 256) {
        int c = idx / 1089, rem = idx - c*1089;
        int r = rem / 33, cc = rem - r*33;
        int hi = hin0 + r, wi = win0 + cc;
        float v = 0.f;
        if ((unsigned)hi < (unsigned)Hin && (unsigned)wi < (unsigned)Win)
            v = ib[(size_t)c*Hin*Win + hi*Win + wi];
        tile[c*33*34 + r*34 + cc] = v;
    }
    __syncthreads();

    float accA[16], accB[4];
    #pragma unroll
    for (int co = 0; co < 16; ++co) accA[co] = bA[co];
    #pragma unroll
    for (int co = 0; co < 4; ++co) accB[co] = bB[co];

    #pragma unroll
    for (int ci = 0; ci < 3; ++ci) {
        float vv[9];
        const float* tb = tile + ci*33*34;
        #pragma unroll
        for (int kh = 0; kh < 3; ++kh)
            #pragma unroll
            for (int kw = 0; kw < 3; ++kw)
                vv[kh*3+kw] = tb[(ty*2 + kh)*34 + tx*2 + kw];
        #pragma unroll
        for (int co = 0; co < 16; ++co) {
            const float* wp = wA + co*27 + ci*9;
            #pragma unroll
            for (int k = 0; k < 9; ++k) accA[co] = fmaf(vv[k], wp[k], accA[co]);
        }
        #pragma unroll
        for (int co = 0; co < 4; ++co) {
            const float* wp = wB + co*27 + ci*9;
            #pragma unroll
            for (int k = 0; k < 9; ++k) accB[co] = fmaf(vv[k], wp[k], accB[co]);
        }
    }
    size_t px = (size_t)ho*Wout + wo;
    #pragma unroll
    for (int co = 0; co < 16; ++co)
        outA[((size_t)(b*16 + co))*Hout*Wout + px] = gelu_t(accA[co]);
    #pragma unroll
    for (int co = 0; co < 4; ++co)
        outB[((size_t)(b*4 + co))*Hout*Wout + px] = gelu_t(accB[co]);
}

// ---------------- layer-2 convs: plane p2 (16->32, split co 2x16) + global g2 (4->8) ----------------
__global__ __launch_bounds__(256) void conv_pg2_k(
    const float* __restrict__ f1, const float* __restrict__ pw2, const float* __restrict__ pb2, float* __restrict__ f2,
    const float* __restrict__ g1, const float* __restrict__ gw2, const float* __restrict__ gb2, float* __restrict__ g2)
{
    __shared__ float tile[8*33*34];   // 35.9 KB
    int z = blockIdx.z;
    if (z < 32) {
        int b = z >> 1, half = z & 1;
        conv_dev2<16,16,2,8>(f1 + (size_t)b*16*12544, pw2 + half*2304, pb2 + half*16,
                             f2 + ((size_t)(b*32 + half*16))*3136,
                             112,112, 56,56, blockIdx.x, blockIdx.y, 0, tile);
    } else {
        conv_dev2<4,8,2,4>(g1, gw2, gb2, g2, 112,112, 56,56, blockIdx.x, blockIdx.y, z-32, tile);
    }
}

// ---------------- layer-3: plane p3 DIRECT (32->4, NHWC out) + global g3 (8->16, LDS) ----------------
__global__ __launch_bounds__(256) void conv_pg3_k(
    const float* __restrict__ f2, const float* __restrict__ pw3, const float* __restrict__ pb3, float4* __restrict__ fmap4,
    const float* __restrict__ g2, const float* __restrict__ gw3, const float* __restrict__ gb3, float* __restrict__ g3)
{
    __shared__ float tile[8*33*34];
    int z = blockIdx.z;
    if (z < 16) {
        int b = z;
        int idx = blockIdx.x*256 + threadIdx.x;
        if (idx >= 3136) return;
        int ho = idx / 56, wo = idx - ho*56;
        const float* ib = f2 + (size_t)b*32*3136;
        float acc[4];
        #pragma unroll
        for (int co = 0; co < 4; ++co) acc[co] = pb3[co];
        for (int ci = 0; ci < 32; ++ci) {
            const float* ic = ib + (size_t)ci*3136;
            #pragma unroll
            for (int kh = 0; kh < 3; ++kh) {
                int hi = ho - 1 + kh;
                if ((unsigned)hi >= 56u) continue;
                #pragma unroll
                for (int kw = 0; kw < 3; ++kw) {
                    int wi = wo - 1 + kw;
                    if ((unsigned)wi >= 56u) continue;
                    float v = ic[hi*56 + wi];
                    int wofs = ci*9 + kh*3 + kw;
                    #pragma unroll
                    for (int co = 0; co < 4; ++co)
                        acc[co] = fmaf(v, pw3[co*288 + wofs], acc[co]);
                }
            }
        }
        float4 o;
        o.x = gelu_t(acc[0]); o.y = gelu_t(acc[1]);
        o.z = gelu_t(acc[2]); o.w = gelu_t(acc[3]);
        fmap4[(size_t)b*3136 + idx] = o;
    } else {
        if (blockIdx.x >= 4) return;
        int bx = blockIdx.x & 1, by = blockIdx.x >> 1;
        conv_dev2<8,16,2,8>(g2, gw3, gb3, g3, 56,56, 28,28, bx, by, z-16, tile);
    }
}

// ================= K4: g4 (392 blocks) + patch fill (16384 blocks) =================
// Patch fill: tap spacing is exactly 1.0 pixel -> all 64 taps of a point share
// one fractional weight pair and lie on an integer 9x9 window. Per wave:
// cooperatively load the 9x9 float4 window into LDS (zero-fill OOB == validity
// masking), then each lane blends its 4 corners with shared wx/wy weights.
__global__ __launch_bounds__(256) void k4_k(
    const float* __restrict__ g3, const float* __restrict__ w4,
    const float* __restrict__ b4, float* __restrict__ g4o,
    const float4* __restrict__ fmap4, const float* __restrict__ points,
    unsigned short* __restrict__ C)
{
    __shared__ float4 pt[4*81];   // 5.2 KB: 4 waves x 9x9 window
    int bid = blockIdx.x;
    int tid = threadIdx.x;
    if (bid < 392) {
        int idx = bid*256 + tid;
        int co = idx & 31;
        int t = idx >> 5;
        int b = t / 196, px = t - b*196;
        int ho = px / 14, wo = px - ho*14;
        const float* src = g3 + (size_t)b*16*784;
        const float* wp = w4 + co*144;
        float acc = b4[co];
        for (int ci = 0; ci < 16; ++ci) {
            #pragma unroll
            for (int kh = 0; kh < 3; ++kh) {
                int hi = ho*2 - 1 + kh;
                if ((unsigned)hi >= 28u) continue;
                #pragma unroll
                for (int kw = 0; kw < 3; ++kw) {
                    int wi = wo*2 - 1 + kw;
                    if ((unsigned)wi >= 28u) continue;
                    acc = fmaf(src[ci*784 + hi*28 + wi], wp[ci*9 + kh*3 + kw], acc);
                }
            }
        }
        g4o[(size_t)b*6272 + px*32 + co] = gelu_t(acc);
    } else {
        int task = (bid - 392)*256 + tid;     // M*64 tasks, exact
        int wv = tid >> 6, lane = tid & 63;
        size_t m = (size_t)(task >> 6);       // wave-uniform point index
        int ij = task & 63;
        int i = ij >> 3, j = ij & 7;          // i: x tap index, j: y tap index
        int b = (int)(m >> 12);
        float px = points[m*2], py = points[m*2+1];
        // ix = 55*px + (i-3.5): integer tap spacing -> shared fractional weights
        float X = fmaf(px, 55.f, -3.5f);      // = ix at i=0
        float Y = fmaf(py, 55.f, -3.5f);
        float xbf = floorf(X), ybf = floorf(Y);
        int xbase = (int)xbf, ybase = (int)ybf;
        float wx1 = X - xbf, wx0 = 1.f - wx1;
        float wy1 = Y - ybf, wy0 = 1.f - wy1;
        const float4* fb = fmap4 + (size_t)b*3136;
        float4* tp = pt + wv*81;

        // cooperative load: 81 float4 (rows = y, cols = x), zero-fill OOB
        {
            int r = lane / 9, c = lane - r*9;
            int y = ybase + r, x = xbase + c;
            float4 v = {0.f, 0.f, 0.f, 0.f};
            if ((unsigned)x < 56u && (unsigned)y < 56u) v = fb[y*56 + x];
            tp[lane] = v;
            int idx2 = 64 + lane;
            if (idx2 < 81) {
                int r2 = idx2 / 9, c2 = idx2 - r2*9;
                int y2 = ybase + r2, x2 = xbase + c2;
                float4 v2 = {0.f, 0.f, 0.f, 0.f};
                if ((unsigned)x2 < 56u && (unsigned)y2 < 56u) v2 = fb[y2*56 + x2];
                tp[idx2] = v2;
            }
        }
        __syncthreads();

        float4 f00 = tp[j*9 + i];
        float4 f10 = tp[j*9 + i + 1];
        float4 f01 = tp[j*9 + 9 + i];
        float4 f11 = tp[j*9 + 9 + i + 1];
        float4 v;
        v.x = wy0*(wx0*f00.x + wx1*f10.x) + wy1*(wx0*f01.x + wx1*f11.x);
        v.y = wy0*(wx0*f00.y + wx1*f10.y) + wy1*(wx0*f01.y + wx1*f11.y);
        v.z = wy0*(wx0*f00.z + wx1*f10.z) + wy1*(wx0*f01.z + wx1*f11.z);
        v.w = wy0*(wx0*f00.w + wx1*f10.w) + wy1*(wx0*f01.w + wx1*f11.w);
        // interleaved patch layout: stored col 256 + ij*4 + c  (bhw1 permuted to match)
        ushort4 o;
        o.x = f2bf(v.x); o.y = f2bf(v.y); o.z = f2bf(v.z); o.w = f2bf(v.w);
        *(ushort4*)(C + m*512 + 256 + ij*4) = o;
    }
}

// ---------------- g5 + avgpool: 32->64, 14->7, s2; atomic pool into gc ----------------
__global__ __launch_bounds__(256) void g5_k(
    const float* __restrict__ g4o, const float* __restrict__ w5,
    const float* __restrict__ b5, float* __restrict__ gc)
{
    int idx = blockIdx.x*256 + threadIdx.x;      // 196 blocks, exact
    int co = idx & 63;
    int t = idx >> 6;
    int b = t / 49, px = t - b*49;
    int ho = px / 7, wo = px - ho*7;
    const float* src = g4o + (size_t)b*6272;
    const float* wp = w5 + co*288;
    float acc = b5[co];
    for (int ci = 0; ci < 32; ++ci) {
        #pragma unroll
        for (int kh = 0; kh < 3; ++kh) {
            int hi = ho*2 - 1 + kh;
            if ((unsigned)hi >= 14u) continue;
            #pragma unroll
            for (int kw = 0; kw < 3; ++kw) {
                int wi = wo*2 - 1 + kw;
                if ((unsigned)wi >= 14u) continue;
                acc = fmaf(src[(hi*14 + wi)*32 + ci], wp[ci*9 + kh*3 + kw], acc);
            }
        }
    }
    atomicAdd(&gc[b*64 + co], gelu_t(acc) * (1.0f/49.0f));
}

// ---------------- hgc: effective head bias  hgc[b][n] = hb1[n] + sum_c gc[b,c]*hw1[n,512+c] ----------------
__global__ __launch_bounds__(256) void hgc_k(
    const float* __restrict__ gc, const float* __restrict__ hw1,
    const float* __restrict__ hb1, float* __restrict__ hgc)
{
    int idx = blockIdx.x*256 + threadIdx.x;   // 32 blocks = 8192
    int b = idx >> 9, n = idx & 511;
    const float* g = gc + b*64;
    const float* w = hw1 + (size_t)n*576 + 512;
    float s = hb1[n];
    #pragma unroll
    for (int c = 0; c < 64; ++c) s = fmaf(g[c], w[c], s);
    hgc[idx] = s;
}

// ---------------- weight conversions (bhw1 col-permuted for k in [256,512)) + out init + gc zero ----------------
__global__ void cvtall_k(const float* __restrict__ lw1, const float* __restrict__ lw2,
                         const float* __restrict__ hw1, unsigned short* __restrict__ blw1,
                         unsigned short* __restrict__ blw2, unsigned short* __restrict__ bhw1,
                         float* __restrict__ out, const float* __restrict__ b2,
                         float* __restrict__ gc){
    int i = blockIdx.x*blockDim.x + threadIdx.x;
    if (i < M_TOT) out[i] = b2[0];
    if (i < 1024) gc[i] = 0.f;
    if (i < 256*64) {
        int r = i >> 6, c = i & 63;
        blw1[i] = (c < 48) ? f2bf(lw1[r*48 + c]) : 0;
        return;
    }
    int j = i - 256*64;
    if (j < 256*256) { blw2[j] = f2bf(lw2[j]); return; }
    j -= 256*256;
    if (j < 512*576) {
        int n = j / 576, k = j - n*576;
        int src_k = k;
        if (k >= 256 && k < 512) {
            int s = k - 256;
            src_k = 256 + (s & 3)*64 + (s >> 2);   // stored ij*4+c  <-  semantic c*64+ij
        }
        bhw1[j] = f2bf(hw1[(size_t)n*576 + src_k]);
    }
}

// ================= mlp12: embed(shared) + mlp1 + mlp2 -> fused cols 0..255, M-strip 128 =================
// pe computed ONCE into LDS (no 4x redundant sinf); gemm2 B direct from global (L2-hot).
__global__ __launch_bounds__(512) void mlp12_k(
    const float* __restrict__ points,
    const unsigned short* __restrict__ W1, const float* __restrict__ b1,
    const unsigned short* __restrict__ W2, const float* __restrict__ b2,
    unsigned short* __restrict__ C)
{
    __shared__ unsigned short Pe[128*64];    // 16 KB, swizzled (phys chunk = seg ^ (row&7))
    __shared__ unsigned short Hd[128*256];   // 64 KB
    int tid = threadIdx.x;
    int wv = tid >> 6, lane = tid & 63;
    int q = lane >> 4, lr = lane & 15;
    int mi = wv >> 2, ni = wv & 3;
    size_t m0 = (size_t)blockIdx.x * 128;

    // ---- embed -> Pe (each chunk computed once) ----
    #pragma unroll
    for (int it = 0; it < 2; ++it) {
        int idx = it*512 + tid;
        int row = idx >> 3, seg = idx & 7;
        size_t m = m0 + row;
        float px = points[m*2], py = points[m*2+1];
        union { s8v v; unsigned short u[8]; } pk;
        #pragma unroll
        for (int j = 0; j < 8; ++j) {
            int k = seg*8 + j;
            unsigned short val = 0;
            if (k < 48) {
                int i2 = k >> 2, rr = k & 3;
                float f = (float)(1 << i2);
                float p = (rr & 1) ? py : px;
                float s = f * p;
                val = f2bf((rr < 2) ? __sinf(s) : __cosf(s));
            }
            pk.u[j] = val;
        }
        *(s8v*)(Pe + (row*8 + (seg ^ (row & 7)))*8) = pk.v;
    }
    __syncthreads();

    // ---- gemm1: hid = gelu(pe @ lw1^T + b1), K=64, A from Pe ----
    f4v acc1[4][4];
    #pragma unroll
    for (int i = 0; i < 4; ++i)
        #pragma unroll
        for (int j = 0; j < 4; ++j) acc1[i][j] = (f4v){0.f,0.f,0.f,0.f};

    #pragma unroll
    for (int kb = 0; kb < 2; ++kb) {
        int seg = kb*4 + q;
        s8v a[4], b[4];
        #pragma unroll
        for (int t = 0; t < 4; ++t) {
            int row = mi*64 + t*16 + lr;
            a[t] = *(const s8v*)(Pe + (row*8 + (seg ^ (row & 7)))*8);
        }
        #pragma unroll
        for (int t = 0; t < 4; ++t) {
            int n = ni*64 + t*16 + lr;
            b[t] = *(const s8v*)(W1 + n*64 + seg*8);
        }
        #pragma unroll
        for (int mt = 0; mt < 4; ++mt)
            #pragma unroll
            for (int nt = 0; nt < 4; ++nt)
                acc1[mt][nt] = __builtin_amdgcn_mfma_f32_16x16x32_bf16(a[mt], b[nt], acc1[mt][nt], 0, 0, 0);
    }
    {
        float b1v[4];
        #pragma unroll
        for (int nt = 0; nt < 4; ++nt) b1v[nt] = b1[ni*64 + nt*16 + lr];
        #pragma unroll
        for (int mt = 0; mt < 4; ++mt)
            #pragma unroll
            for (int r4 = 0; r4 < 4; ++r4) {
                int row = mi*64 + mt*16 + q*4 + r4;
                #pragma unroll
                for (int nt = 0; nt < 4; ++nt) {
                    int col = ni*64 + nt*16 + lr;
                    float v = gelu_t(acc1[mt][nt][r4] + b1v[nt]);
                    int p = (col >> 3) ^ (row & 7);
                    Hd[(row*32 + p)*8 + (col & 7)] = f2bf(v);
                }
            }
    }
    __syncthreads();

    // ---- gemm2: pf = hid @ lw2^T + b2, A from Hd, B direct from global ----
    f4v acc2[4][4];
    #pragma unroll
    for (int i = 0; i < 4; ++i)
        #pragma unroll
        for (int j = 0; j < 4; ++j) acc2[i][j] = (f4v){0.f,0.f,0.f,0.f};

    #pragma unroll 2
    for (int kt = 0; kt < 8; ++kt) {
        s8v a[4], b[4];
        #pragma unroll
        for (int t = 0; t < 4; ++t) {
            int n = ni*64 + t*16 + lr;
            b[t] = *(const s8v*)(W2 + (size_t)n*256 + kt*32 + q*8);
        }
        #pragma unroll
        for (int t = 0; t < 4; ++t) {
            int row = mi*64 + t*16 + lr;
            int p = (kt*4 + q) ^ (row & 7);
            a[t] = *(const s8v*)(Hd + (row*32 + p)*8);
        }
        #pragma unroll
        for (int mt = 0; mt < 4; ++mt)
            #pragma unroll
            for (int nt = 0; nt < 4; ++nt)
                acc2[mt][nt] = __builtin_amdgcn_mfma_f32_16x16x32_bf16(a[mt], b[nt], acc2[mt][nt], 0, 0, 0);
    }
    {
        float b2v[4];
        #pragma unroll
        for (int nt = 0; nt < 4; ++nt) b2v[nt] = b2[ni*64 + nt*16 + lr];
        #pragma unroll
        for (int mt = 0; mt < 4; ++mt)
            #pragma unroll
            for (int r4 = 0; r4 < 4; ++r4) {
                size_t m = m0 + mi*64 + mt*16 + q*4 + r4;
                #pragma unroll
                for (int nt = 0; nt < 4; ++nt) {
                    int n = ni*64 + nt*16 + lr;
                    C[m*512 + n] = f2bf(acc2[mt][nt][r4] + b2v[nt]);
                }
            }
    }
}

// ================= head: 256 thr, tile 128x256 (4 waves x 64x128), BK=64, K=512 =================
// R5 structure kept (GLL + XOR-swizzled single-buffer LDS). VALU surgery,
// corrected: K-loop fully unrolled with the k-step as COMPILE-TIME pointer
// arithmetic on the global source (builtin offset stays 0 — R6 showed the
// offset arg also shifts the LDS destination). LDS fragment offsets hoisted;
// s_setprio(1) around the MFMA cluster.
__global__ __launch_bounds__(256, 2) void gemm_hd_k(
    const unsigned short* __restrict__ A,
    const unsigned short* __restrict__ W,
    const float* __restrict__ hgc, const float* __restrict__ w2,
    float* __restrict__ out)
{
    __shared__ unsigned short As[128*64];    // 16 KB
    __shared__ unsigned short Bs[256*64];    // 32 KB
    __shared__ float red[4*64];              // 1 KB
    int tid = threadIdx.x;
    int wv = tid >> 6, lane = tid & 63;
    int q = lane >> 4, lr = lane & 15;
    int wm = wv >> 1, wn = wv & 1;           // 2x2 wave grid, wave tile 64x128
    size_t m0 = (size_t)blockIdx.x * 128;
    int nbase = blockIdx.y * 256;
    int bimg = (int)(m0 >> 12);              // image index, uniform per block

    // staging addresses (loop-invariant; k-step applied as constant pointer math)
    const unsigned short* srcA[4]; int dA[4];
    #pragma unroll
    for (int r = 0; r < 4; ++r) {
        int f = r*256 + tid;
        int row = f >> 3, sl = (f & 7) ^ (row & 7);
        srcA[r] = A + (m0 + row)*512 + sl*8;
        dA[r] = f*8;
    }
    const unsigned short* srcB[8]; int dB[8];
    #pragma unroll
    for (int r = 0; r < 8; ++r) {
        int f = r*256 + tid;
        int row = f >> 3, sl = (f & 7) ^ (row & 7);
        srcB[r] = W + (size_t)(nbase + row)*576 + sl*8;
        dB[r] = f*8;
    }

    // LDS fragment element-offsets, invariant across the whole K loop
    int aoff[2][4], boff[2][8];
    #pragma unroll
    for (int kk = 0; kk < 2; ++kk) {
        #pragma unroll
        for (int t = 0; t < 4; ++t) {
            int row = wm*64 + t*16 + lr;
            aoff[kk][t] = (row*8 + ((kk*4 + q) ^ (row & 7)))*8;
        }
        #pragma unroll
        for (int t = 0; t < 8; ++t) {
            int row = wn*128 + t*16 + lr;
            boff[kk][t] = (row*8 + ((kk*4 + q) ^ (row & 7)))*8;
        }
    }

    f4v acc[4][8];
    #pragma unroll
    for (int i = 0; i < 4; ++i)
        #pragma unroll
        for (int j = 0; j < 8; ++j) acc[i][j] = (f4v){0.f,0.f,0.f,0.f};

    // one K-step; KS is a literal so srcX[r] + KS*64 is a constant fold
#define HD_KSTEP(KS) { \
    GLL(srcA[0] + (KS)*64, As + dA[0]); GLL(srcA[1] + (KS)*64, As + dA[1]); \
    GLL(srcA[2] + (KS)*64, As + dA[2]); GLL(srcA[3] + (KS)*64, As + dA[3]); \
    GLL(srcB[0] + (KS)*64, Bs + dB[0]); GLL(srcB[1] + (KS)*64, Bs + dB[1]); \
    GLL(srcB[2] + (KS)*64, Bs + dB[2]); GLL(srcB[3] + (KS)*64, Bs + dB[3]); \
    GLL(srcB[4] + (KS)*64, Bs + dB[4]); GLL(srcB[5] + (KS)*64, Bs + dB[5]); \
    GLL(srcB[6] + (KS)*64, Bs + dB[6]); GLL(srcB[7] + (KS)*64, Bs + dB[7]); \
    __syncthreads(); \
    __builtin_amdgcn_s_setprio(1); \
    _Pragma("unroll") \
    for (int kk = 0; kk < 2; ++kk) { \
        s8v a[4], b[8]; \
        _Pragma("unroll") \
        for (int t = 0; t < 4; ++t) a[t] = *(const s8v*)(As + aoff[kk][t]); \
        _Pragma("unroll") \
        for (int t = 0; t < 8; ++t) b[t] = *(const s8v*)(Bs + boff[kk][t]); \
        _Pragma("unroll") \
        for (int mt = 0; mt < 4; ++mt) \
            _Pragma("unroll") \
            for (int nt = 0; nt < 8; ++nt) \
                acc[mt][nt] = __builtin_amdgcn_mfma_f32_16x16x32_bf16(a[mt], b[nt], acc[mt][nt], 0, 0, 0); \
    } \
    __builtin_amdgcn_s_setprio(0); \
    __syncthreads(); \
}

    HD_KSTEP(0) HD_KSTEP(1) HD_KSTEP(2) HD_KSTEP(3)
    HD_KSTEP(4) HD_KSTEP(5) HD_KSTEP(6) HD_KSTEP(7)
#undef HD_KSTEP

    float bv[8], w2v[8];
    #pragma unroll
    for (int nt = 0; nt < 8; ++nt) {
        int n = nbase + wn*128 + nt*16 + lr;
        bv[nt] = hgc[bimg*512 + n];
        w2v[nt] = w2[n];
    }
    #pragma unroll
    for (int mt = 0; mt < 4; ++mt)
        #pragma unroll
        for (int r4 = 0; r4 < 4; ++r4) {
            int ml = mt*16 + q*4 + r4;       // row within wave's 64
            float s = 0.f;
            #pragma unroll
            for (int nt = 0; nt < 8; ++nt)
                s += gelu_t(acc[mt][nt][r4] + bv[nt]) * w2v[nt];
            #pragma unroll
            for (int off = 8; off > 0; off >>= 1) s += __shfl_down(s, off, 16);
            if (lr == 0) red[wv*64 + ml] = s;
        }
    __syncthreads();
    if (tid < 128) {
        int wmI = tid >> 6, ml = tid & 63;
        float t = red[(wmI*2)*64 + ml] + red[(wmI*2 + 1)*64 + ml];
        atomicAdd(&out[m0 + tid], t);
    }
}

extern "C" void kernel_launch(void* const* d_in, const int* in_sizes, int n_in,
                              void* d_out, int out_size, void* d_ws, size_t ws_size,
                              hipStream_t stream) {
    const float* points = (const float*)d_in[0];
    const float* images = (const float*)d_in[1];
    const float* pw1 = (const float*)d_in[2];  const float* pb1 = (const float*)d_in[3];
    const float* pw2 = (const float*)d_in[4];  const float* pb2 = (const float*)d_in[5];
    const float* pw3 = (const float*)d_in[6];  const float* pb3 = (const float*)d_in[7];
    const float* gw1 = (const float*)d_in[8];  const float* gb1 = (const float*)d_in[9];
    const float* gw2 = (const float*)d_in[10]; const float* gb2 = (const float*)d_in[11];
    const float* gw3 = (const float*)d_in[12]; const float* gb3 = (const float*)d_in[13];
    const float* gw4 = (const float*)d_in[14]; const float* gb4 = (const float*)d_in[15];
    const float* gw5 = (const float*)d_in[16]; const float* gb5 = (const float*)d_in[17];
    const float* lw1 = (const float*)d_in[18]; const float* lb1 = (const float*)d_in[19];
    const float* lw2 = (const float*)d_in[20]; const float* lb2 = (const float*)d_in[21];
    const float* hw1 = (const float*)d_in[22]; const float* hb1 = (const float*)d_in[23];
    const float* hw2 = (const float*)d_in[24]; const float* hb2 = (const float*)d_in[25];
    float* out = (float*)d_out;

    // ---- workspace layout ----
    char* base = (char*)d_ws;
    unsigned short* fused_b = (unsigned short*)base;                       // M*512 bf16 = 67 MB
    float4* fmap4 = (float4*)(fused_b + (size_t)M_TOT*512);                // 16*3136 float4
    float* g3   = (float*)(fmap4 + (size_t)16*3136);                       // 16*16*784 (OUT of alias region)
    float* g4o  = g3 + (size_t)16*16*784;                                  // 16*196*32 (OUT of alias region)
    float* gc   = g4o + (size_t)16*32*196;                                 // 1024
    float* hgc  = gc + 1024;                                               // 16*512
    unsigned short* blw1 = (unsigned short*)(hgc + 16*512);                // 256*64
    unsigned short* blw2 = blw1 + 256*64;                                  // 256*256
    unsigned short* bhw1 = blw2 + 256*256;                                 // 512*576 (col-permuted)
    // conv temps f1,f2,g1,g2 alias inside fused region (dead before k4 writes fused):
    float* ct = (float*)base;
    float* f1 = ct;
    float* f2 = f1 + (size_t)16*16*112*112;
    float* g1 = f2 + (size_t)16*32*56*56;
    float* g2 = g1 + (size_t)16*4*112*112;

    cvtall_k<<<1472, 256, 0, stream>>>(lw1, lw2, hw1, blw1, blw2, bhw1, out, hb2, gc);
    conv_dual_k<<<dim3(7,7,16), 256, 0, stream>>>(images, pw1, pb1, gw1, gb1, f1, g1);
    conv_pg2_k<<<dim3(4,4,48), 256, 0, stream>>>(f1, pw2, pb2, f2, g1, gw2, gb2, g2);
    conv_pg3_k<<<dim3(13,1,32), 256, 0, stream>>>(f2, pw3, pb3, fmap4, g2, gw3, gb3, g3);
    // K4: g4 + patch fill (fill depends only on pg3; runs at full-machine parallelism)
    k4_k<<<392 + 16384, 256, 0, stream>>>(g3, gw4, gb4, g4o, fmap4, points, fused_b);
    g5_k<<<196, 256, 0, stream>>>(g4o, gw5, gb5, gc);   // includes avgpool via atomics
    hgc_k<<<32, 256, 0, stream>>>(gc, hw1, hb1, hgc);   // fold gc into head bias (fp32)
    // mlp12: pure GEMM now (pe shared in LDS), writes fused cols 0..255
    mlp12_k<<<M_TOT/128, 512, 0, stream>>>(points, blw1, lb1, blw2, lb2, fused_b);
    gemm_hd_k<<<dim3(M_TOT/128, 2), 256, 0, stream>>>(fused_b, bhw1, hgc, hw2, out);
}